// Round 13
// baseline (85.157 us; speedup 1.0000x reference)
//
#include <hip/hip_runtime.h>
#include <stdint.h>

// ---- problem constants ----
#define NPIX   4194304      // 8*512*1024
#define KSEL   1258291      // int(NPIX * 0.3)
#define HWSZ   524288       // 512*1024 (class-plane stride in elements)
#define NCLS   20

#define CE_BLOCKS 4096      // 256 consecutive float4-groups (1024 px) per block
#define HB_BLOCKS 512
#define HB_ITERS  4         // (NPIX/8) / (HB_BLOCKS*256)

// bf16-code histogram window: [2^-4, 2^8) = codes [123<<7, 135<<7) = 1536 codes.
// CE max ~ logsumexp-min(pred) < 16 << 256; threshold ~ 1 >> 0.0625, so the
// window covers every selectable value exactly (1 bin == 1 bf16 value).
#define CBASE  15744        // (123 << 7)
#define NBIN   1536
#define CHUNK  6            // NBIN / 256

// ---- workspace layout (bytes) ----
#define OFF_H    0          // uint[8][1536]  XCD-sharded bf16-code histogram
#define MEMSET_LEN 49152
#define OFF_PSUM 49152      // double[4096]   per-block CE partial sums
#define OFF_CE   131072     // ushort[NPIX]   CE values as bf16 bits

typedef float          f4  __attribute__((ext_vector_type(4)));
typedef int            i4  __attribute__((ext_vector_type(4)));
typedef unsigned short us4 __attribute__((ext_vector_type(4)));
typedef unsigned short us8 __attribute__((ext_vector_type(8)));

__device__ __forceinline__ unsigned short f2bf(float x) {
    unsigned u = __float_as_uint(x);
    // round-to-nearest-even; x >= 0, finite
    return (unsigned short)((u + 0x7FFFu + ((u >> 16) & 1u)) >> 16);
}
__device__ __forceinline__ float bf2f(unsigned b) {
    return __uint_as_float(b << 16);
}

__device__ __forceinline__ double block_reduce_d(double d, double* lred) {
    __syncthreads();  // protect lred reuse across calls
    for (int off = 32; off > 0; off >>= 1) d += __shfl_down(d, off);
    int wid  = threadIdx.x >> 6;
    int lane = threadIdx.x & 63;
    if (lane == 0) lred[wid] = d;
    __syncthreads();
    double r = 0.0;
    if (threadIdx.x == 0) {
        for (int i = 0; i < 4; ++i) r += lred[i];
    }
    return r;  // valid on thread 0 only
}

// ---- kernel 1: per-pixel CE (f32 math, bf16 store). 4 px/thread,
//      launch_bounds(256,8) = 64-VGPR cap -> 8 blocks/CU = 32 waves/CU.
//      Wave reads 1 KB contiguous per class-plane. ----
__global__ __launch_bounds__(256, 8) void ce_kernel(const float* __restrict__ pred,
                                                    const int* __restrict__ tgt,
                                                    unsigned short* __restrict__ ce,
                                                    double* __restrict__ psum) {
    __shared__ double lred[4];
    int t = threadIdx.x, w = t >> 6, l = t & 63;
    int blk = blockIdx.x;
    int g0 = blk << 8;              // first float4-group of this block (256/block)
    int p0 = g0 << 2;
    int b  = p0 >> 19;              // batch index (1024 px/block divides 524288)
    int hw = p0 & (HWSZ - 1);
    const float* base = pred + (size_t)b * (size_t)(NCLS * HWSZ) + hw;

    // wave w owns groups [w*64, w*64+64) contiguously; thread takes lane l
    int go = (w << 6) + l;

    i4 tt = ((const i4*)tgt)[g0 + go];

    float s[4], vt[4];
#pragma unroll
    for (int i = 0; i < 4; ++i) { s[i] = 0.f; vt[i] = 0.f; }

#pragma unroll
    for (int c = 0; c < NCLS; ++c) {
        f4 a = ((const f4*)(base + (size_t)c * HWSZ))[go];
        s[0] += __expf(a.x);
        s[1] += __expf(a.y);
        s[2] += __expf(a.z);
        s[3] += __expf(a.w);
        if (c == tt.x) vt[0] = a.x;
        if (c == tt.y) vt[1] = a.y;
        if (c == tt.z) vt[2] = a.z;
        if (c == tt.w) vt[3] = a.w;
    }

    float r[4];
#pragma unroll
    for (int i = 0; i < 4; ++i)
        r[i] = fmaxf(__logf(s[i]) - vt[i], 0.0f);   // >= 0: bit order == value order

    us4 u;
    u.x = f2bf(r[0]); u.y = f2bf(r[1]); u.z = f2bf(r[2]); u.w = f2bf(r[3]);
    ((us4*)ce)[g0 + go] = u;

    double d = (double)r[0] + (double)r[1] + (double)r[2] + (double)r[3];
    d = block_reduce_d(d, lred);
    if (t == 0) psum[blk] = d;
}

// ---- kernel 2: exact bf16-code histogram (1536 bins), wave-private LDS,
//      XCD-sharded global flush. ONE read of the CE array. (FROZEN R12) ----
__global__ __launch_bounds__(256) void hist_kernel(const unsigned short* __restrict__ ce,
                                                   unsigned* __restrict__ h) {
    __shared__ unsigned lh[4][NBIN];   // 24 KB wave-private sub-hists
    int t = threadIdx.x, w = t >> 6, blk = blockIdx.x;
    for (int i = t; i < 4 * NBIN; i += 256) ((unsigned*)lh)[i] = 0u;
    __syncthreads();

    const us8* ce8 = (const us8*)ce;
    int tid0 = blk * 256 + t;
#pragma unroll
    for (int it = 0; it < HB_ITERS; ++it) {
        us8 x = ce8[tid0 + it * (HB_BLOCKS * 256)];
#pragma unroll
        for (int j = 0; j < 8; ++j) {
            int bin = (int)(unsigned)x[j] - CBASE;
            bin = (bin < 0) ? 0 : ((bin > NBIN - 1) ? NBIN - 1 : bin);
            atomicAdd(&lh[w][bin], 1u);
        }
    }
    __syncthreads();
    unsigned* hs = h + ((unsigned)blk & 7u) * NBIN;   // XCD shard
    for (int i = t; i < NBIN; i += 256) {
        unsigned c = lh[0][i] + lh[1][i] + lh[2][i] + lh[3][i];
        if (c) atomicAdd(&hs[i], c);
    }
}

// ---- kernel 3: finalize (one block): merge shards, suffix-scan 1536 bins,
//      exact weighted top-k sum + mean (FROZEN R12 except psum count) ----
__global__ __launch_bounds__(256) void fin_kernel(const unsigned* __restrict__ h,
                                                  const double* __restrict__ psum,
                                                  float* __restrict__ out) {
    __shared__ unsigned tmp[256];
    __shared__ unsigned sbin, skrem;
    __shared__ double lred[4];
    int t = threadIdx.x;

    // thread t owns bins [t*CHUNK, t*CHUNK+CHUNK)
    unsigned cnt[CHUNK];
    unsigned lsum = 0;
#pragma unroll
    for (int j = 0; j < CHUNK; ++j) {
        unsigned c = 0;
#pragma unroll
        for (int sdx = 0; sdx < 8; ++sdx) c += h[sdx * NBIN + t * CHUNK + j];
        cnt[j] = c;
        lsum += c;
    }
    tmp[t] = lsum;
    __syncthreads();
    // inclusive suffix scan over per-thread sums
    for (int off = 1; off < 256; off <<= 1) {
        unsigned add = (t + off < 256) ? tmp[t + off] : 0u;
        __syncthreads();
        tmp[t] += add;
        __syncthreads();
    }
    unsigned cum = tmp[t] - lsum;   // count in bins strictly above my chunk
    for (int j = CHUNK - 1; j >= 0; --j) {
        unsigned hv = cnt[j];
        if (cum < (unsigned)KSEL && cum + hv >= (unsigned)KSEL) {
            sbin = (unsigned)(t * CHUNK + j);
            skrem = (unsigned)KSEL - cum;
        }
        cum += hv;
    }
    __syncthreads();
    unsigned b = sbin, krem = skrem;

    // exact weighted sum over bins strictly above b (each bin = one bf16 value)
    double wsum = 0.0;
#pragma unroll
    for (int j = 0; j < CHUNK; ++j) {
        int bin = t * CHUNK + j;
        if (bin > (int)b && cnt[j])
            wsum += (double)cnt[j] * (double)bf2f((unsigned)(bin + CBASE));
    }
    double top = block_reduce_d(wsum, lred);

    double a = 0.0;
    for (int i = t; i < CE_BLOCKS; i += 256) a += psum[i];
    double total = block_reduce_d(a, lred);

    if (t == 0) {
        top += (double)krem * (double)bf2f(b + CBASE);
        double loss = total / ((double)NPIX + 1e-12) + top / (double)KSEL;
        out[0] = (float)loss;
    }
}

extern "C" void kernel_launch(void* const* d_in, const int* in_sizes, int n_in,
                              void* d_out, int out_size, void* d_ws, size_t ws_size,
                              hipStream_t stream) {
    const float* pred = (const float*)d_in[0];
    const int*   tgt  = (const int*)d_in[1];
    float* out = (float*)d_out;
    char* ws = (char*)d_ws;
    unsigned* h    = (unsigned*)(ws + OFF_H);
    double*   psum = (double*)(ws + OFF_PSUM);
    unsigned short* ce = (unsigned short*)(ws + OFF_CE);

    hipMemsetAsync(ws, 0, MEMSET_LEN, stream);
    ce_kernel<<<CE_BLOCKS, 256, 0, stream>>>(pred, tgt, ce, psum);
    hist_kernel<<<HB_BLOCKS, 256, 0, stream>>>(ce, h);
    fin_kernel<<<1, 256, 0, stream>>>(h, psum, out);
}

// Round 14
// 76.160 us; speedup vs baseline: 1.1181x; 1.1181x over previous
//
#include <hip/hip_runtime.h>
#include <stdint.h>

// ---- problem constants ----
#define NPIX   4194304      // 8*512*1024
#define KSEL   1258291      // int(NPIX * 0.3)
#define HWSZ   524288       // 512*1024 (class-plane stride in elements)
#define NCLS   20

#define CE_BLOCKS 2048      // 512 consecutive float4-groups (2048 px) per block

// bf16-code histogram window: [2^-4, 2^8) = codes [123<<7, 135<<7) = 1536 codes.
// CE max ~ logsumexp-min(pred) < 16 << 256; threshold ~ 1 >> 0.0625, so the
// window covers every selectable value exactly (1 bin == 1 bf16 value).
#define CBASE  15744        // (123 << 7)
#define NBIN   1536
#define CHUNK  6            // NBIN / 256

// ---- workspace layout (bytes) ----
#define OFF_H    0          // uint[8][1536]  XCD-sharded bf16-code histogram
#define MEMSET_LEN 49152
#define OFF_PSUM 49152      // double[2048]   per-block CE partial sums

typedef float          f4  __attribute__((ext_vector_type(4)));
typedef int            i4  __attribute__((ext_vector_type(4)));

__device__ __forceinline__ unsigned short f2bf(float x) {
    unsigned u = __float_as_uint(x);
    // round-to-nearest-even; x >= 0, finite
    return (unsigned short)((u + 0x7FFFu + ((u >> 16) & 1u)) >> 16);
}
__device__ __forceinline__ float bf2f(unsigned b) {
    return __uint_as_float(b << 16);
}

__device__ __forceinline__ double block_reduce_d(double d, double* lred) {
    __syncthreads();  // protect lred reuse across calls
    for (int off = 32; off > 0; off >>= 1) d += __shfl_down(d, off);
    int wid  = threadIdx.x >> 6;
    int lane = threadIdx.x & 63;
    if (lane == 0) lred[wid] = d;
    __syncthreads();
    double r = 0.0;
    if (threadIdx.x == 0) {
        for (int i = 0; i < 4; ++i) r += lred[i];
    }
    return r;  // valid on thread 0 only
}

// ---- kernel 1: per-pixel CE + fused 1536-bin bf16-code histogram.
//      R12 memory structure (8 px/thread, wave reads 2 KB/class), NO CE store.
//      amdgpu_waves_per_eu(4,4) pins occupancy to 4 waves/EU (16 waves/CU)
//      so the register allocator keeps the full 128-VGPR budget (R8/R10's
//      heuristic over-shoot is disallowed by the max bound). ----
__global__ __launch_bounds__(256) __attribute__((amdgpu_waves_per_eu(4, 4)))
void ce_kernel(const float* __restrict__ pred,
               const int* __restrict__ tgt,
               double* __restrict__ psum,
               unsigned* __restrict__ h) {
    __shared__ unsigned lh[4][NBIN];   // 24 KB wave-private sub-hists
    __shared__ double lred[4];
    int t = threadIdx.x, w = t >> 6, l = t & 63;
    for (int i = t; i < 4 * NBIN; i += 256) ((unsigned*)lh)[i] = 0u;
    __syncthreads();

    int blk = blockIdx.x;
    int g0 = blk << 9;              // first float4-group of this block (512/block)
    int p0 = g0 << 2;
    int b  = p0 >> 19;              // batch index (2048 px/block divides 524288)
    int hw = p0 & (HWSZ - 1);
    const float* base = pred + (size_t)b * (size_t)(NCLS * HWSZ) + hw;

    // wave w owns groups [w*128, w*128+128); thread takes l and l+64
    int go0 = (w << 7) + l;
    int go1 = go0 + 64;

    i4 tt0 = ((const i4*)tgt)[g0 + go0];
    i4 tt1 = ((const i4*)tgt)[g0 + go1];

    float s[8], vt[8];
#pragma unroll
    for (int i = 0; i < 8; ++i) { s[i] = 0.f; vt[i] = 0.f; }

#pragma unroll
    for (int c = 0; c < NCLS; ++c) {
        const f4* pc = (const f4*)(base + (size_t)c * HWSZ);
        f4 a = pc[go0];
        f4 d = pc[go1];
        s[0] += __expf(a.x);
        s[1] += __expf(a.y);
        s[2] += __expf(a.z);
        s[3] += __expf(a.w);
        s[4] += __expf(d.x);
        s[5] += __expf(d.y);
        s[6] += __expf(d.z);
        s[7] += __expf(d.w);
        if (c == tt0.x) vt[0] = a.x;
        if (c == tt0.y) vt[1] = a.y;
        if (c == tt0.z) vt[2] = a.z;
        if (c == tt0.w) vt[3] = a.w;
        if (c == tt1.x) vt[4] = d.x;
        if (c == tt1.y) vt[5] = d.y;
        if (c == tt1.z) vt[6] = d.z;
        if (c == tt1.w) vt[7] = d.w;
    }

    double d = 0.0;
#pragma unroll
    for (int i = 0; i < 8; ++i) {
        float r = fmaxf(__logf(s[i]) - vt[i], 0.0f);  // >= 0
        d += (double)r;
        int bin = (int)(unsigned)f2bf(r) - CBASE;
        bin = (bin < 0) ? 0 : ((bin > NBIN - 1) ? NBIN - 1 : bin);
        atomicAdd(&lh[w][bin], 1u);
    }

    __syncthreads();
    unsigned* hs = h + ((unsigned)blk & 7u) * NBIN;   // XCD-sharded flush
    for (int i = t; i < NBIN; i += 256) {
        unsigned c = lh[0][i] + lh[1][i] + lh[2][i] + lh[3][i];
        if (c) atomicAdd(&hs[i], c);
    }
    d = block_reduce_d(d, lred);
    if (t == 0) psum[blk] = d;
}

// ---- kernel 2: finalize (one block): merge shards, suffix-scan 1536 bins,
//      exact weighted top-k sum + mean (FROZEN R12) ----
__global__ __launch_bounds__(256) void fin_kernel(const unsigned* __restrict__ h,
                                                  const double* __restrict__ psum,
                                                  float* __restrict__ out) {
    __shared__ unsigned tmp[256];
    __shared__ unsigned sbin, skrem;
    __shared__ double lred[4];
    int t = threadIdx.x;

    // thread t owns bins [t*CHUNK, t*CHUNK+CHUNK)
    unsigned cnt[CHUNK];
    unsigned lsum = 0;
#pragma unroll
    for (int j = 0; j < CHUNK; ++j) {
        unsigned c = 0;
#pragma unroll
        for (int sdx = 0; sdx < 8; ++sdx) c += h[sdx * NBIN + t * CHUNK + j];
        cnt[j] = c;
        lsum += c;
    }
    tmp[t] = lsum;
    __syncthreads();
    // inclusive suffix scan over per-thread sums
    for (int off = 1; off < 256; off <<= 1) {
        unsigned add = (t + off < 256) ? tmp[t + off] : 0u;
        __syncthreads();
        tmp[t] += add;
        __syncthreads();
    }
    unsigned cum = tmp[t] - lsum;   // count in bins strictly above my chunk
    for (int j = CHUNK - 1; j >= 0; --j) {
        unsigned hv = cnt[j];
        if (cum < (unsigned)KSEL && cum + hv >= (unsigned)KSEL) {
            sbin = (unsigned)(t * CHUNK + j);
            skrem = (unsigned)KSEL - cum;
        }
        cum += hv;
    }
    __syncthreads();
    unsigned b = sbin, krem = skrem;

    // exact weighted sum over bins strictly above b (each bin = one bf16 value)
    double wsum = 0.0;
#pragma unroll
    for (int j = 0; j < CHUNK; ++j) {
        int bin = t * CHUNK + j;
        if (bin > (int)b && cnt[j])
            wsum += (double)cnt[j] * (double)bf2f((unsigned)(bin + CBASE));
    }
    double top = block_reduce_d(wsum, lred);

    double a = 0.0;
    for (int i = t; i < CE_BLOCKS; i += 256) a += psum[i];
    double total = block_reduce_d(a, lred);

    if (t == 0) {
        top += (double)krem * (double)bf2f(b + CBASE);
        double loss = total / ((double)NPIX + 1e-12) + top / (double)KSEL;
        out[0] = (float)loss;
    }
}

extern "C" void kernel_launch(void* const* d_in, const int* in_sizes, int n_in,
                              void* d_out, int out_size, void* d_ws, size_t ws_size,
                              hipStream_t stream) {
    const float* pred = (const float*)d_in[0];
    const int*   tgt  = (const int*)d_in[1];
    float* out = (float*)d_out;
    char* ws = (char*)d_ws;
    unsigned* h    = (unsigned*)(ws + OFF_H);
    double*   psum = (double*)(ws + OFF_PSUM);

    hipMemsetAsync(ws, 0, MEMSET_LEN, stream);
    ce_kernel<<<CE_BLOCKS, 256, 0, stream>>>(pred, tgt, psum, h);
    fin_kernel<<<1, 256, 0, stream>>>(h, psum, out);
}